// Round 10
// baseline (435.039 us; speedup 1.0000x reference)
//
#include <hip/hip_runtime.h>
#include <hip/hip_bf16.h>

#define KS 5
#define K3 125

typedef __attribute__((ext_vector_type(8))) short short8;
typedef __attribute__((ext_vector_type(4))) float floatx4;

__device__ inline unsigned enc_f(float f) {
    int b = __float_as_int(f);
    return (b >= 0) ? ((unsigned)b | 0x80000000u) : ~((unsigned)b);
}

__device__ inline unsigned short f2bf(float f) {
    unsigned u = __float_as_uint(f);
    u += 0x7FFFu + ((u >> 16) & 1u);  // RNE
    return (unsigned short)(u >> 16);
}
__device__ inline float bf2f(unsigned short h) {
    return __uint_as_float((unsigned)h << 16);
}
__device__ inline unsigned pack2bf(float a, float b) {
    return (unsigned)f2bf(a) | ((unsigned)f2bf(b) << 16);
}

// ---------------------------------------------------------------------------
// Inline basis helpers
// ---------------------------------------------------------------------------
__device__ inline void edge_basis(const float* __restrict__ pseudo, int e,
                                  float* bs, int* ks) {
    float fr[3];
    int bot[3];
#pragma unroll
    for (int d = 0; d < 3; ++d) {
        float v = pseudo[e * 3 + d] * (float)(KS - 1);
        float fl = fminf(floorf(v), (float)(KS - 2));
        fr[d] = v - fl;
        bot[d] = (int)fl;
    }
    const int strides[3] = {1, KS, KS * KS};
#pragma unroll
    for (int s = 0; s < 8; ++s) {
        float b = 1.f;
        int w = 0;
#pragma unroll
        for (int d = 0; d < 3; ++d) {
            int bit = (s >> d) & 1;
            b *= bit ? fr[d] : (1.f - fr[d]);
            w += (bot[d] + bit) * strides[d];
        }
        bs[s] = b;
        ks[s] = w;
    }
}

__device__ inline void edge_fracs(const float* __restrict__ pseudo, int e, float* bs) {
    float fr[3];
#pragma unroll
    for (int d = 0; d < 3; ++d) {
        float v = pseudo[e * 3 + d] * (float)(KS - 1);
        float fl = fminf(floorf(v), (float)(KS - 2));
        fr[d] = v - fl;
    }
#pragma unroll
    for (int s = 0; s < 8; ++s) {
        float b = 1.f;
#pragma unroll
        for (int d = 0; d < 3; ++d) b *= ((s >> d) & 1) ? fr[d] : (1.f - fr[d]);
        bs[s] = b;
    }
}

__device__ inline int edge_bucket(const float* __restrict__ pseudo, int e) {
    int kb = 0;
#pragma unroll
    for (int d = 0; d < 3; ++d) {
        float v = pseudo[e * 3 + d] * (float)(KS - 1);
        int fl = (int)fminf(floorf(v), (float)(KS - 2));
        kb += fl << (2 * d);
    }
    return kb;
}

// ---------------------------------------------------------------------------
// Pre-pass 1 (merged): hist partials + degree (blocks 0..679)
// + cluster member lists (blocks 680..764)
// + weight transpose-convert via LDS (blocks 765..1639, one per k-slice).
// degi atomicAdd's return value = edge rank within dst (stored to posArr).
// ---------------------------------------------------------------------------
__global__ __launch_bounds__(256) void pre1(
    const float* __restrict__ p0, const float* __restrict__ p1,
    const float* __restrict__ p2, const float* __restrict__ p3,
    const int* __restrict__ d0, const int* __restrict__ d1,
    const int* __restrict__ d2, const int* __restrict__ d3,
    const int* __restrict__ c0, const int* __restrict__ c1,
    const int* __restrict__ c2, const int* __restrict__ c3,
    const float* __restrict__ w12, const float* __restrict__ w2,
    const float* __restrict__ w3, const float* __restrict__ w4,
    const float* __restrict__ w5, const float* __restrict__ w6,
    const float* __restrict__ w7,
    int* __restrict__ hpart, int* __restrict__ degi,
    int* __restrict__ ccnt, int* __restrict__ clist,
    short* __restrict__ Wt, int* __restrict__ posArr) {
    __shared__ float wls[64 * 65];  // 16.6 KB transpose buffer (wcvt blocks)
    __shared__ int h[64];
    int b = blockIdx.x;
    int t = threadIdx.x;
    if (b >= 765) {  // ---- wcvt: one block per (tensor, k) slice ----
        int sl = b - 765;
        const float* srcp;
        int IC, OC, lgI, lgO, per;
        size_t obase;
        if (sl < 125) {
            IC = 32; OC = 32; lgI = 5; lgO = 5; per = 1024;
            srcp = w12 + (size_t)sl * 1024;
            obase = (size_t)sl * 1024;
        } else if (sl < 250) {
            int k = sl - 125;
            IC = 32; OC = 64; lgI = 5; lgO = 6; per = 2048;
            srcp = w2 + (size_t)k * 2048;
            obase = 128000 + (size_t)k * 2048;
        } else {
            int q = sl - 250;
            int ts = q / 125;
            int k = q - ts * 125;
            const float* Ws[5] = {w3, w4, w5, w6, w7};
            IC = 64; OC = 64; lgI = 6; lgO = 6; per = 4096;
            srcp = Ws[ts] + (size_t)k * 4096;
            obase = 384000 + (size_t)ts * 512000 + (size_t)k * 4096;
        }
        for (int r = t; r < per; r += 256) {  // coalesced fp32 load
            int i = r >> lgO, o = r & (OC - 1);
            wls[i * (OC + 1) + o] = srcp[r];
        }
        __syncthreads();
        for (int j = t; j < per; j += 256) {  // coalesced bf16 store
            int o = j >> lgI, i = j & (IC - 1);
            Wt[obase + j] = (short)f2bf(wls[i * (OC + 1) + o]);
        }
        return;
    }
    if (b >= 680) {  // ---- clist part ----
        int idx = (b - 680) * 256 + t;
        int j, cof, nof;
        const int* cl;
        if (idx < 16384)      { j = idx;         cl = c0; cof = 0;    nof = 0; }
        else if (idx < 20480) { j = idx - 16384; cl = c1; cof = 4096; nof = 16384; }
        else if (idx < 21504) { j = idx - 20480; cl = c2; cof = 5120; nof = 20480; }
        else if (idx < 21760) { j = idx - 21504; cl = c3; cof = 5376; nof = 21504; }
        else return;
        int c = cl[j];
        int slot = atomicAdd(&ccnt[cof + c], 1) & 3;  // defensive: slot < 4
        clist[nof + c * 4 + slot] = j;
        return;
    }
    // ---- hist + degree part (block b == hist row b) ----
    int l, lb, E, dof, eof_;
    const float* ps;
    const int* ds;
    if (b < 512)      { l = 0; lb = b;       ps = p0; ds = d0; E = 131072; dof = 0;     eof_ = 0; }
    else if (b < 640) { l = 1; lb = b - 512; ps = p1; ds = d1; E = 32768;  dof = 16384; eof_ = 131072; }
    else if (b < 672) { l = 2; lb = b - 640; ps = p2; ds = d2; E = 8192;   dof = 20480; eof_ = 163840; }
    else              { l = 3; lb = b - 672; ps = p3; ds = d3; E = 2048;   dof = 21504; eof_ = 172032; }
    if (t < 64) h[t] = 0;
    __syncthreads();
    int e = lb * 256 + t;
    if (e < E) {
        atomicAdd(&h[edge_bucket(ps, e)], 1);
        int rel = atomicAdd(&degi[dof + ds[e]], 1);  // rank within dst = free
        posArr[eof_ + e] = rel;
    }
    __syncthreads();
    if (t < 64) hpart[b * 64 + t] = h[t];  // unconditional: full row written
}

// ---------------------------------------------------------------------------
// Pre-pass 2 (merged): CSR scan + tile layout + parallel bbase. (verified R5)
// ---------------------------------------------------------------------------
__global__ __launch_bounds__(1024) void pre2(const int* __restrict__ hpart,
                                             int* __restrict__ bbase,
                                             int* __restrict__ tileOf,
                                             int* __restrict__ pack,
                                             const int* __restrict__ degi,
                                             int* __restrict__ off) {
    int b = blockIdx.x;
    int t = threadIdx.x;
    __shared__ int ls[1024];
    __shared__ int aux[192];
    if (b < 4) {  // ---- CSR scan ----
        const int Nv[4] = {16384, 4096, 1024, 256};
        const int DOFv[4] = {0, 16384, 20480, 21504};
        const int OFFv[4] = {0, 16385, 20482, 21507};
        int l = b;
        int n = Nv[l];
        const int* d = degi + DOFv[l];
        int* o = off + OFFv[l];
        int per = (n + 1023) >> 10;
        int beg = t * per;
        int end = (beg + per < n) ? beg + per : n;
        int s = 0;
        for (int j = beg; j < end; ++j) s += d[j];
        ls[t] = s;
        __syncthreads();
        for (int dd = 1; dd < 1024; dd <<= 1) {
            int v = (t >= dd) ? ls[t - dd] : 0;
            __syncthreads();
            ls[t] += v;
            __syncthreads();
        }
        int base = (t == 0) ? 0 : ls[t - 1];
        for (int j = beg; j < end; ++j) {
            o[j] = base;
            base += d[j];
        }
        if (t == 1023) o[n] = ls[1023];
    } else {  // ---- tile layout + per-row bases (parallel) ----
        const int TBv[4] = {0, 2112, 2688, 2880};
        const int MTv[4] = {2112, 576, 192, 96};
        const int HBv[4] = {0, 512, 640, 672};
        const int NBv[4] = {512, 128, 32, 8};
        int l = b - 4;
        int tileBase = TBv[l];
        int hb = HBv[l], nb = NBv[l];
        int bucket = t & 63, seg = t >> 6;
        int rps = (nb + 15) >> 4;
        int r0 = seg * rps;
        int r1 = r0 + rps;
        if (r1 > nb) r1 = nb;
        int ssum = 0;
        for (int lb = r0; lb < r1; ++lb) ssum += hpart[(hb + lb) * 64 + bucket];
        ls[seg * 64 + bucket] = ssum;
        __syncthreads();
        int pre = 0;
        for (int s2 = 0; s2 < seg; ++s2) pre += ls[s2 * 64 + bucket];
        if (seg == 15) aux[bucket] = pre + ssum;
        __syncthreads();
        if (t < 64) aux[64 + t] = (aux[t] + 63) >> 6;
        __syncthreads();
        for (int d = 1; d < 64; d <<= 1) {
            int v = 0;
            if (t < 64 && t >= d) v = aux[64 + t - d];
            __syncthreads();
            if (t < 64) aux[64 + t] += v;
            __syncthreads();
        }
        if (t < 64) {
            int cnt = aux[t];
            int tiles = (cnt + 63) >> 6;
            int tb = tileBase + aux[64 + t] - tiles;
            int gstart = tb * 64;
            aux[128 + t] = gstart;
            for (int q = 0; q < tiles; ++q) tileOf[tb + q] = t;
            for (int idx = gstart + cnt; idx < (tb + tiles) * 64; ++idx) pack[idx] = -1;
            if (t == 63) {
                for (int q = tileBase + aux[64 + 63]; q < tileBase + MTv[l]; ++q)
                    tileOf[q] = -1;
            }
        }
        __syncthreads();
        int run = aux[128 + bucket] + pre;
        for (int lb = r0; lb < r1; ++lb) {
            bbase[(hb + lb) * 64 + bucket] = run;
            run += hpart[(hb + lb) * 64 + bucket];
        }
    }
}

// ---------------------------------------------------------------------------
// Pre-pass 3: counting sort (zero global atomics — bucket bases from bbase,
// absolute pos = csr[dst] + rel-rank from pre1).
// ---------------------------------------------------------------------------
__global__ __launch_bounds__(256) void scatter_pos_all(
    const float* __restrict__ p0, const float* __restrict__ p1,
    const float* __restrict__ p2, const float* __restrict__ p3,
    const int* __restrict__ d0, const int* __restrict__ d1,
    const int* __restrict__ d2, const int* __restrict__ d3,
    const int* __restrict__ bbase, const int* __restrict__ csr,
    int* __restrict__ pack, int* __restrict__ posArr,
    int* __restrict__ esrt) {
    int b = blockIdx.x;
    int l, lb, E, eof_, cof;
    const float* ps;
    const int* ds;
    if (b < 512)      { l = 0; lb = b;       ps = p0; ds = d0; E = 131072; eof_ = 0;      cof = 0; }
    else if (b < 640) { l = 1; lb = b - 512; ps = p1; ds = d1; E = 32768;  eof_ = 131072; cof = 16385; }
    else if (b < 672) { l = 2; lb = b - 640; ps = p2; ds = d2; E = 8192;   eof_ = 163840; cof = 20482; }
    else              { l = 3; lb = b - 672; ps = p3; ds = d3; E = 2048;   eof_ = 172032; cof = 21507; }
    const int* csrL = csr + cof;
    __shared__ int h[64], lbk[64], gb[64], sh[64];
    __shared__ int sp[256];
    __shared__ unsigned char skk[256];
    int t = threadIdx.x;
    int e = lb * 256 + t;
    int kb = -1;
    if (t < 64) {
        h[t] = 0;
        gb[t] = bbase[b * 64 + t];
    }
    __syncthreads();
    if (e < E) {
        kb = edge_bucket(ps, e);
        atomicAdd(&h[kb], 1);
        int p = csrL[ds[e]] + posArr[eof_ + e];  // absolute pos, no atomic
        posArr[eof_ + e] = p;
        if (l == 0 && p >= 0 && p < 131072) esrt[p] = e;
    }
    __syncthreads();
    if (t < 64) sh[t] = h[t];
    __syncthreads();
    for (int d = 1; d < 64; d <<= 1) {
        int v = (t < 64 && t >= d) ? sh[t - d] : 0;
        __syncthreads();
        if (t < 64) sh[t] += v;
        __syncthreads();
    }
    if (t < 64) {
        lbk[t] = sh[t] - h[t];
        h[t] = 0;
    }
    __syncthreads();
    if (kb >= 0) {
        int ppos = lbk[kb] + atomicAdd(&h[kb], 1);
        sp[ppos] = e;
        skk[ppos] = (unsigned char)kb;
    }
    __syncthreads();
    int Pb = E - lb * 256;
    if (Pb > 256) Pb = 256;
    if (t < Pb) {
        int k = skk[t];
        pack[gb[k] + (t - lbk[k])] = sp[t];
    }
}

// ---------------------------------------------------------------------------
// Fused conv1 (in_c = 1) + finalize with 1-ahead software pipeline (R9).
// ---------------------------------------------------------------------------
__global__ __launch_bounds__(256) void conv1_fin(
    const float* __restrict__ x, const int* __restrict__ src,
    const float* __restrict__ pseudo, const int* __restrict__ esrt,
    const int* __restrict__ off, const float* __restrict__ W,
    const float* __restrict__ R, const float* __restrict__ B,
    float* __restrict__ out, int n, int Emax) {
    const int lane = threadIdx.x & 63;
    const int wid = threadIdx.x >> 6;
    const int sub = lane >> 5;
    const int o = lane & 31;
    int j = (blockIdx.x * 4 + wid) * 2 + sub;
    if (j >= n) return;
    int b0 = off[j], b1 = off[j + 1];
    if (b0 < 0) b0 = 0;
    if (b1 > Emax) b1 = Emax;
    float acc = 0.f;
    float px = 0.f, py = 0.f, pz = 0.f, xs = 0.f;
    if (b0 < b1) {
        int e0 = esrt[b0];
        px = pseudo[e0 * 3];
        py = pseudo[e0 * 3 + 1];
        pz = pseudo[e0 * 3 + 2];
        xs = x[src[e0]];
    }
    for (int r = b0; r < b1; ++r) {
        float cpx = px, cpy = py, cpz = pz, cxs = xs;
        if (r + 1 < b1) {  // prefetch next edge's operands
            int e1 = esrt[r + 1];
            px = pseudo[e1 * 3];
            py = pseudo[e1 * 3 + 1];
            pz = pseudo[e1 * 3 + 2];
            xs = x[src[e1]];
        }
        float fr[3];
        int bot[3];
        float pv[3] = {cpx, cpy, cpz};
#pragma unroll
        for (int d = 0; d < 3; ++d) {
            float v = pv[d] * (float)(KS - 1);
            float fl = fminf(floorf(v), (float)(KS - 2));
            fr[d] = v - fl;
            bot[d] = (int)fl;
        }
        const int strides[3] = {1, KS, KS * KS};
        float w = 0.f;
#pragma unroll
        for (int s = 0; s < 8; ++s) {
            float bsv = 1.f;
            int wk = 0;
#pragma unroll
            for (int d = 0; d < 3; ++d) {
                int bit = (s >> d) & 1;
                bsv *= bit ? fr[d] : (1.f - fr[d]);
                wk += (bot[d] + bit) * strides[d];
            }
            w = fmaf(bsv, W[wk * 32 + o], w);
        }
        acc = fmaf(w, cxs, acc);
    }
    float d = fmaxf((float)(b1 - b0), 1.f);
    float v = acc / d + x[j] * R[o] + B[o];
    out[(size_t)j * 32 + o] = (v > 0.f) ? v : expm1f(v);
}

// ---------------------------------------------------------------------------
// MFMA bucket-tile conv, R10: TWO tiles per block, double-buffered LDS,
// phase-interleaved schedule. The per-block serial chain (pack -> src/pseudo
// -> x-gather -> stage -> barrier -> MFMA) was 24 us/dispatch at 4% MfmaUtil
// (R7 DR diagnostic): latency-bound. Both tiles' context chains issue
// up-front; phases alternate buffers so tile B's staging overlaps tile A's
// MFMA with exactly one barrier per phase. Invalid tail tiles degrade to
// zero-work (e=-1, kb clamped) so barriers stay uniform.
// ---------------------------------------------------------------------------
template <int IN_C, int OUT_C>
__global__ __launch_bounds__(256, 4) void mfma_conv(
    const float* __restrict__ x, const int* __restrict__ src,
    const float* __restrict__ pseudo, const int* __restrict__ pack,
    const int* __restrict__ tileOf, const int* __restrict__ pos,
    const short* __restrict__ Wt, unsigned short* __restrict__ y, int tileBase,
    int Emax) {
    constexpr int PH = (IN_C == 64) ? 4 : 2;  // staging phases per tile
    constexpr int SPP = 8 / PH;               // slots per phase
    constexpr int KPH = SPP * IN_C;           // K per phase (=128)
    constexpr int KP = KPH + 8;               // padded row (shorts) = 136
    constexpr int NT = OUT_C / 16;
    constexpr int IP = IN_C / 4;
    __shared__ short As[2][64 * KP];          // 2 x 17.4 KB double buffer
    __shared__ int posL[2][64];
    const int tid = threadIdx.x;
    const int t0 = tileBase + 2 * blockIdx.x;
    int kb0 = tileOf[t0], kb1 = tileOf[t0 + 1];
    bool v0 = (kb0 >= 0 && kb0 < 64), v1 = (kb1 >= 0 && kb1 < 64);
    if (!v0 && !v1) return;  // block-uniform
    if (!v0) kb0 = 0;        // clamp: zero-work tile reads valid Wt, discards
    if (!v1) kb1 = 0;
    kb0 = __builtin_amdgcn_readfirstlane(kb0);
    kb1 = __builtin_amdgcn_readfirstlane(kb1);
    const int kbase[2] = {(kb0 & 3) + 5 * ((kb0 >> 2) & 3) + 25 * ((kb0 >> 4) & 3),
                          (kb1 & 3) + 5 * ((kb1 >> 2) & 3) + 25 * ((kb1 >> 4) & 3)};
    const int eLoc = tid >> 2, part = tid & 3;
    const int wave = tid >> 6, lane = tid & 63;
    const int quad = lane >> 4, lm = lane & 15;
    // ---- context loads for BOTH tiles (independent chains, issued up-front)
    int e[2];
    e[0] = v0 ? pack[(size_t)t0 * 64 + eLoc] : -1;
    e[1] = v1 ? pack[(size_t)(t0 + 1) * 64 + eLoc] : -1;
    float bs[2][8];
    float4 xq[2][IP / 4];
#pragma unroll
    for (int q = 0; q < 2; ++q) {
        if (e[q] >= Emax) e[q] = -1;  // defensive
        if (e[q] >= 0) edge_fracs(pseudo, e[q], bs[q]);
        else {
#pragma unroll
            for (int s = 0; s < 8; ++s) bs[q][s] = 0.f;
        }
        if (part == 0) posL[q][eLoc] = (e[q] >= 0) ? pos[e[q]] : -1;
#pragma unroll
        for (int g = 0; g < IP / 4; ++g)
            xq[q][g] = (e[q] >= 0)
                           ? *(const float4*)(x + (size_t)src[e[q]] * IN_C + part * IP + g * 4)
                           : make_float4(0.f, 0.f, 0.f, 0.f);
    }
    floatx4 acc[2][NT];
#pragma unroll
    for (int q = 0; q < 2; ++q)
#pragma unroll
        for (int nt = 0; nt < NT; ++nt) acc[q][nt] = (floatx4){0.f, 0.f, 0.f, 0.f};
    // ---- 2*PH interleaved phases: stage(p) | barrier | MFMA(p).
    // Buffer p&1; tile p&1; phase p>>1. The next iteration's stage targets
    // the OTHER buffer, so MFMA(p) and stage(p+1) overlap; the single barrier
    // per phase protects buffer reuse at p+2.
#pragma unroll
    for (int p = 0; p < 2 * PH; ++p) {
        const int q = p & 1;
        const int ph = p >> 1;
        short* Ab = As[q];
        // ---- stage slots [ph*SPP, ph*SPP+SPP) of tile q ----
#pragma unroll
        for (int s2 = 0; s2 < SPP; ++s2) {
            const float b = bs[q][ph * SPP + s2];
            short* rowp = &Ab[eLoc * KP + s2 * IN_C + part * IP];
#pragma unroll
            for (int g = 0; g < IP / 4; ++g) {
                unsigned lo = pack2bf(b * xq[q][g].x, b * xq[q][g].y);
                unsigned hi = pack2bf(b * xq[q][g].z, b * xq[q][g].w);
                *(uint2*)(rowp + 4 * g) = make_uint2(lo, hi);
            }
        }
        __syncthreads();
        // ---- MFMA over this phase's K for tile q ----
        const short* myrow = &Ab[(wave * 16 + lm) * KP];
#pragma unroll
        for (int kstep = 0; kstep < KPH / 32; ++kstep) {
            const int kg = kstep * 32;
            const int s2 = kg / IN_C;
            const int i0 = kg % IN_C;
            const int s = ph * SPP + s2;
            const int ks = kbase[q] + (s & 1) + 5 * ((s >> 1) & 1) + 25 * ((s >> 2) & 1);
            short8 a = *(const short8*)&myrow[kg + quad * 8];
#pragma unroll
            for (int nt = 0; nt < NT; ++nt) {
                const short* bp =
                    Wt + ((size_t)ks * OUT_C + nt * 16 + lm) * IN_C + i0 + quad * 8;
                short8 bfr = *(const short8*)bp;
                acc[q][nt] = __builtin_amdgcn_mfma_f32_16x16x32_bf16(a, bfr, acc[q][nt], 0, 0, 0);
            }
        }
    }
    // ---- epilogue: write both tiles ----
#pragma unroll
    for (int q = 0; q < 2; ++q) {
#pragma unroll
        for (int nt = 0; nt < NT; ++nt) {
#pragma unroll
            for (int r = 0; r < 4; ++r) {
                int row = wave * 16 + quad * 4 + r;
                int p = posL[q][row];
                if (p >= 0 && p < Emax)
                    y[(size_t)p * OUT_C + nt * 16 + lm] = f2bf(acc[q][nt][r]);
            }
        }
    }
}

// ---------------------------------------------------------------------------
// Finalize (gather): out = (sum of dst's CSR run of bf16 y)/deg + x@R + B, ELU.
// ---------------------------------------------------------------------------
template <int OUT_C>
__device__ inline float csr_sum(const int* __restrict__ off,
                                const unsigned short* __restrict__ y, int j, int o,
                                float& dcount) {
    int b0 = off[j], b1 = off[j + 1];
    if (b0 < 0) b0 = 0;
    if (b1 < b0) b1 = b0;
    dcount = fmaxf((float)(b1 - b0), 1.f);
    float s0 = 0.f, s1 = 0.f, s2 = 0.f, s3 = 0.f;
    int r = b0;
    for (; r + 4 <= b1; r += 4) {
        s0 += bf2f(y[(size_t)(r + 0) * OUT_C + o]);
        s1 += bf2f(y[(size_t)(r + 1) * OUT_C + o]);
        s2 += bf2f(y[(size_t)(r + 2) * OUT_C + o]);
        s3 += bf2f(y[(size_t)(r + 3) * OUT_C + o]);
    }
    for (; r < b1; ++r) s0 += bf2f(y[(size_t)r * OUT_C + o]);
    return (s0 + s1) + (s2 + s3);
}

template <int IN_C, int OUT_C>
__global__ __launch_bounds__(256) void fin_gather_k(
    const float* __restrict__ xin, const float* __restrict__ R,
    const float* __restrict__ B, const int* __restrict__ off,
    const unsigned short* __restrict__ y, float* __restrict__ out, int n) {
    const int lane = threadIdx.x & 63;
    const int wid = threadIdx.x >> 6;
    constexpr int EPW = 64 / OUT_C;
    const int sub = (EPW == 2) ? (lane >> 5) : 0;
    const int o = lane & (OUT_C - 1);
    int j = (blockIdx.x * (blockDim.x >> 6) + wid) * EPW + sub;
    if (j >= n) return;
    float xv = (o < IN_C) ? xin[j * IN_C + o] : 0.f;
    float acc = B[o];
#pragma unroll 4
    for (int i = 0; i < IN_C; ++i) {
        float xi = __shfl(xv, i, OUT_C);
        acc = fmaf(xi, R[i * OUT_C + o], acc);
    }
    float d;
    float s = csr_sum<OUT_C>(off, y, j, o, d);
    float v = s / d + acc;
    out[j * OUT_C + o] = (v > 0.f) ? v : expm1f(v);
}

// ---------------------------------------------------------------------------
// Fused finalize + pool-max: every cluster has exactly 4 members (clist).
// ---------------------------------------------------------------------------
template <int IN_C, int OUT_C>
__global__ __launch_bounds__(256) void fin_pool_k(
    const float* __restrict__ xin, const float* __restrict__ R,
    const float* __restrict__ B, const int* __restrict__ off,
    const unsigned short* __restrict__ y, const int* __restrict__ clist,
    float* __restrict__ out, int nsrc) {
    constexpr int CPB = 256 / (4 * OUT_C);
    const int t = threadIdx.x;
    const int o = t & (OUT_C - 1);
    const int mem = (t / OUT_C) & 3;
    const int g = t / (4 * OUT_C);
    const int c = blockIdx.x * CPB + g;
    int j = clist[c * 4 + mem];
    if (j < 0) j = 0;
    if (j >= nsrc) j = nsrc - 1;  // defensive
    float xv = (o < IN_C) ? xin[(size_t)j * IN_C + o] : 0.f;
    float acc = B[o];
#pragma unroll 4
    for (int i = 0; i < IN_C; ++i) {
        float xi = __shfl(xv, i, OUT_C);
        acc = fmaf(xi, R[i * OUT_C + o], acc);
    }
    float d;
    float s = csr_sum<OUT_C>(off, y, j, o, d);
    float v = s / d + acc;
    v = (v > 0.f) ? v : expm1f(v);
    __shared__ float sh[256];
    sh[t] = v;
    __syncthreads();
    if (mem == 0) {
        const float* base = &sh[g * 4 * OUT_C];
        float r01 = fmaxf(base[o], base[OUT_C + o]);
        float r23 = fmaxf(base[2 * OUT_C + o], base[3 * OUT_C + o]);
        out[(size_t)c * OUT_C + o] = fmaxf(r01, r23);
    }
}

// ---------------------------------------------------------------------------
// Fallback kernels (small-ws path only).
// ---------------------------------------------------------------------------
__global__ __launch_bounds__(256) void conv1_fused(const float* __restrict__ x,
                                                   const int* __restrict__ src,
                                                   const int* __restrict__ dst,
                                                   const float* __restrict__ pseudo,
                                                   const float* __restrict__ W,
                                                   float* __restrict__ out, int E) {
    const int lane = threadIdx.x & 63;
    const int wid = threadIdx.x >> 6;
    const int sub = lane >> 5;
    const int o = lane & 31;
    int e = (blockIdx.x * 4 + wid) * 2 + sub;
    if (e >= E) return;
    float bs[8];
    int ks[8];
    edge_basis(pseudo, e, bs, ks);
    float acc = 0.f;
#pragma unroll
    for (int s = 0; s < 8; ++s) acc = fmaf(bs[s], W[ks[s] * 32 + o], acc);
    atomicAdd(&out[(size_t)dst[e] * 32 + o], acc * x[src[e]]);
}

template <int IN_C, int OUT_C>
__global__ __launch_bounds__(256) void conv_edges_inline(
    const float* __restrict__ x, const int* __restrict__ src,
    const int* __restrict__ dst, const float* __restrict__ pseudo,
    const float* __restrict__ W, float* __restrict__ out, int E) {
    const int lane = threadIdx.x & 63;
    const int wid = threadIdx.x >> 6;
    constexpr int EPW = 64 / OUT_C;
    const int sub = (EPW == 2) ? (lane >> 5) : 0;
    const int o = lane & (OUT_C - 1);
    long e = (long)(blockIdx.x * (blockDim.x >> 6) + wid) * EPW + sub;
    if (e >= E) return;
    float bs[8];
    int ks[8];
    edge_basis(pseudo, e, bs, ks);
    const int s_ = src[e];
    const int d_ = dst[e];
    float xv = (o < IN_C) ? x[s_ * IN_C + o] : 0.f;
    float acc = 0.f;
#pragma unroll
    for (int s = 0; s < 8; ++s) {
        const float b = bs[s];
        const float* Wk = W + (long)ks[s] * IN_C * OUT_C;
#pragma unroll 4
        for (int i = 0; i < IN_C; ++i) {
            float xi = __shfl(xv, i, OUT_C);
            acc = fmaf(b * xi, Wk[i * OUT_C + o], acc);
        }
    }
    atomicAdd(&out[(long)d_ * OUT_C + o], acc);
}

__global__ void deg_kernel(const int* __restrict__ dst, float* __restrict__ deg, int E) {
    int e = blockIdx.x * blockDim.x + threadIdx.x;
    if (e >= E) return;
    atomicAdd(&deg[dst[e]], 1.0f);
}

template <int IN_C, int OUT_C>
__global__ __launch_bounds__(256) void finalize_k(
    const float* __restrict__ xin, const float* __restrict__ R,
    const float* __restrict__ B, const float* __restrict__ deg,
    float* __restrict__ out, int n) {
    const int lane = threadIdx.x & 63;
    const int wid = threadIdx.x >> 6;
    constexpr int EPW = 64 / OUT_C;
    const int sub = (EPW == 2) ? (lane >> 5) : 0;
    const int o = lane & (OUT_C - 1);
    int j = (blockIdx.x * (blockDim.x >> 6) + wid) * EPW + sub;
    if (j >= n) return;
    float xv = (o < IN_C) ? xin[j * IN_C + o] : 0.f;
    float acc = B[o];
#pragma unroll 4
    for (int i = 0; i < IN_C; ++i) {
        float xi = __shfl(xv, i, OUT_C);
        acc = fmaf(xi, R[i * OUT_C + o], acc);
    }
    float d = fmaxf(deg[j], 1.f);
    float v = out[j * OUT_C + o] / d + acc;
    out[j * OUT_C + o] = (v > 0.f) ? v : expm1f(v);
}

__global__ void pool_scatter(const float* __restrict__ h, const int* __restrict__ cluster,
                             unsigned* __restrict__ pool, int n, int logC) {
    int idx = blockIdx.x * blockDim.x + threadIdx.x;
    if (idx >= (n << logC)) return;
    int j = idx >> logC;
    int c = idx & ((1 << logC) - 1);
    atomicMax(&pool[(cluster[j] << logC) + c], enc_f(h[idx]));
}

__global__ void pool_decode(const unsigned* __restrict__ pool, float* __restrict__ out, int total) {
    int idx = blockIdx.x * blockDim.x + threadIdx.x;
    if (idx >= total) return;
    unsigned u = pool[idx];
    int b = (u & 0x80000000u) ? (int)(u & 0x7FFFFFFFu) : (int)(~u);
    out[idx] = __int_as_float(b);
}

// ---------------------------------------------------------------------------
// Head: mean(64x64) -> fc1 -> fc2 -> log_softmax
// ---------------------------------------------------------------------------
__global__ void head_kernel(const float* __restrict__ h, const float* __restrict__ fc1w,
                            const float* __restrict__ fc1b, const float* __restrict__ fc2w,
                            const float* __restrict__ fc2b, float* __restrict__ out) {
    __shared__ float m[64], t[64], u[10];
    int lane = threadIdx.x;
    float s = 0.f;
    for (int j = 0; j < 64; ++j) s += h[j * 64 + lane];
    m[lane] = s * (1.f / 64.f);
    __syncthreads();
    float a = fc1b[lane];
    for (int i = 0; i < 64; ++i) a = fmaf(m[i], fc1w[i * 64 + lane], a);
    t[lane] = a;
    __syncthreads();
    if (lane < 10) {
        float b = fc2b[lane];
        for (int i = 0; i < 64; ++i) b = fmaf(t[i], fc2w[i * 10 + lane], b);
        u[lane] = b;
    }
    __syncthreads();
    if (lane < 10) {
        float mx = u[0];
        for (int i = 1; i < 10; ++i) mx = fmaxf(mx, u[i]);
        float se = 0.f;
        for (int i = 0; i < 10; ++i) se += expf(u[i] - mx);
        out[lane] = u[lane] - mx - logf(se);
    }
}

// ---------------------------------------------------------------------------
// Host side
// ---------------------------------------------------------------------------
static inline int cdiv(int a, int b) { return (a + b - 1) / b; }

extern "C" void kernel_launch(void* const* d_in, const int* in_sizes, int n_in,
                              void* d_out, int out_size, void* d_ws, size_t ws_size,
                              hipStream_t stream) {
    const float* x = (const float*)d_in[0];
    const int* src[4] = {(const int*)d_in[1], (const int*)d_in[5], (const int*)d_in[9], (const int*)d_in[13]};
    const int* dst[4] = {(const int*)d_in[2], (const int*)d_in[6], (const int*)d_in[10], (const int*)d_in[14]};
    const float* pseudo[4] = {(const float*)d_in[3], (const float*)d_in[7], (const float*)d_in[11], (const float*)d_in[15]};
    const int* cluster[4] = {(const int*)d_in[4], (const int*)d_in[8], (const int*)d_in[12], (const int*)d_in[16]};
    const float* Wp[8], *Rp[8], *Bp[8];
    for (int l = 0; l < 8; ++l) {
        Wp[l] = (const float*)d_in[17 + 3 * l];
        Rp[l] = (const float*)d_in[18 + 3 * l];
        Bp[l] = (const float*)d_in[19 + 3 * l];
    }
    const float* fc1w = (const float*)d_in[41];
    const float* fc1b = (const float*)d_in[42];
    const float* fc2w = (const float*)d_in[43];
    const float* fc2b = (const float*)d_in[44];
    float* outp = (float*)d_out;

    const int NS[5] = {16384, 4096, 1024, 256, 64};
    const int ES[4] = {16384 * 8, 4096 * 8, 1024 * 8, 256 * 8};
    const int MT[4] = {2048 + 64, 512 + 64, 128 + 64, 32 + 64};
    const int TB_[4] = {0, 2112, 2112 + 576, 2112 + 576 + 192};
    const int TOT_TILES = 2112 + 576 + 192 + 96;  // 2976
    const int DTOT = 21760;
    const int OFF2[4] = {0, 16385, 20482, 21507};
    const int OFFTOT = 21764;
    const int EBASE[4] = {0, 131072, 163840, 172032};
    const int ETOT = 174080;
    const int NODE_OFF[4] = {0, 16384, 20480, 21504};
    const int CCTOT = 4096 + 1024 + 256 + 64;  // 5440
    const int HTOT = 680;
    const int WT_OFF[7] = {0, 128000, 384000, 896000, 1408000, 1920000, 2432000};
    const int WT_TOT = 2944000;
    const int NSLICE = 875;  // 125 + 125 + 5*125 weight k-slices

    char* w = (char*)d_ws;
    auto take = [&](size_t bytes) -> char* {
        char* r = w;
        w += (bytes + 255) & ~(size_t)255;
        return r;
    };
    float* bufA = (float*)take((size_t)NS[0] * 64 * 4);
    float* bufB = (float*)take((size_t)NS[0] * 64 * 4);
    unsigned* pool = (unsigned*)take((size_t)NS[1] * 64 * 4);  // fallback only
    // ---- contiguous zero-init region: ccnt | degi ----
    char* zbase = w;
    int* ccnt = (int*)take((size_t)CCTOT * 4);
    int* degi = (int*)take((size_t)DTOT * 4);
    size_t zbytes = (size_t)(w - zbase);
    size_t fallbackNeed = (size_t)(w - (char*)d_ws);
    int* tileOf = (int*)take((size_t)TOT_TILES * 4);
    int* hpart = (int*)take((size_t)HTOT * 64 * 4);
    int* bbase = (int*)take((size_t)HTOT * 64 * 4);
    int* pack = (int*)take((size_t)TOT_TILES * 64 * 4);
    int* csr = (int*)take((size_t)OFFTOT * 4);
    int* posArr = (int*)take((size_t)ETOT * 4);
    int* clist = (int*)take((size_t)DTOT * 4);
    int* esrt = (int*)take((size_t)ES[0] * 4);
    short* Wtb = (short*)take((size_t)WT_TOT * 2);
    unsigned short* y = (unsigned short*)take((size_t)ES[0] * 32 * 2);  // 8.4 MB bf16
    size_t need = (size_t)(w - (char*)d_ws);
    bool fast = ws_size >= need;

    const int TB = 256;

    if (fast) {
        // ---------- pre-pass: 1 memset + 3 kernels -------------------------
        (void)hipMemsetAsync(zbase, 0, zbytes, stream);
        pre1<<<765 + NSLICE, 256, 0, stream>>>(
            pseudo[0], pseudo[1], pseudo[2], pseudo[3],
            dst[0], dst[1], dst[2], dst[3],
            cluster[0], cluster[1], cluster[2], cluster[3],
            Wp[1], Wp[2], Wp[3], Wp[4], Wp[5], Wp[6], Wp[7],
            hpart, degi, ccnt, clist, Wtb, posArr);
        pre2<<<8, 1024, 0, stream>>>(hpart, bbase, tileOf, pack, degi, csr);
        scatter_pos_all<<<680, 256, 0, stream>>>(pseudo[0], pseudo[1], pseudo[2], pseudo[3],
                                                 dst[0], dst[1], dst[2], dst[3],
                                                 bbase, csr, pack, posArr, esrt);

        // ---------------- Level 0: conv1 (1->32), conv12 (32->32) ----------
        {
            int n = NS[0];
            const int* off = csr + OFF2[0];
            const int* pos = posArr + EBASE[0];
            conv1_fin<<<cdiv(n, 8), TB, 0, stream>>>(x, src[0], pseudo[0], esrt, off,
                                                     Wp[0], Rp[0], Bp[0], bufA, n, ES[0]);
            mfma_conv<32, 32><<<MT[0] / 2, TB, 0, stream>>>(
                bufA, src[0], pseudo[0], pack, tileOf, pos, Wtb + WT_OFF[0], y, TB_[0], ES[0]);
            fin_pool_k<32, 32><<<NS[1] / 2, TB, 0, stream>>>(
                bufA, Rp[1], Bp[1], off, y, clist + NODE_OFF[0], bufB, NS[0]);
        }
        // ---------------- Level 1: conv2 (32->64), conv3 (64->64) ----------
        {
            int n = NS[1];
            const int* off = csr + OFF2[1];
            const int* pos = posArr + EBASE[1];
            mfma_conv<32, 64><<<MT[1] / 2, TB, 0, stream>>>(
                bufB, src[1], pseudo[1], pack, tileOf, pos, Wtb + WT_OFF[1], y, TB_[1], ES[1]);
            fin_gather_k<32, 64><<<cdiv(n, 4), TB, 0, stream>>>(bufB, Rp[2], Bp[2], off, y, bufA, n);
            mfma_conv<64, 64><<<MT[1] / 2, TB, 0, stream>>>(
                bufA, src[1], pseudo[1], pack, tileOf, pos, Wtb + WT_OFF[2], y, TB_[1], ES[1]);
            fin_pool_k<64, 64><<<NS[2], TB, 0, stream>>>(
                bufA, Rp[3], Bp[3], off, y, clist + NODE_OFF[1], bufB, NS[1]);
        }
        // ---------------- Level 2: conv4, conv5 (64->64) -------------------
        {
            int n = NS[2];
            const int* off = csr + OFF2[2];
            const int* pos = posArr + EBASE[2];
            mfma_conv<64, 64><<<MT[2] / 2, TB, 0, stream>>>(
                bufB, src[2], pseudo[2], pack, tileOf, pos, Wtb + WT_OFF[3], y, TB_[2], ES[2]);
            fin_gather_k<64, 64><<<cdiv(n, 4), TB, 0, stream>>>(bufB, Rp[4], Bp[4], off, y, bufA, n);
            mfma_conv<64, 64><<<MT[2] / 2, TB, 0, stream>>>(
                bufA, src[2], pseudo[2], pack, tileOf, pos, Wtb + WT_OFF[4], y, TB_[2], ES[2]);
            fin_pool_k<64, 64><<<NS[3], TB, 0, stream>>>(
                bufA, Rp[5], Bp[5], off, y, clist + NODE_OFF[2], bufB, NS[2]);
        }
        // ---------------- Level 3: conv6, conv7 (64->64) -------------------
        {
            int n = NS[3];
            const int* off = csr + OFF2[3];
            const int* pos = posArr + EBASE[3];
            mfma_conv<64, 64><<<MT[3] / 2, TB, 0, stream>>>(
                bufB, src[3], pseudo[3], pack, tileOf, pos, Wtb + WT_OFF[5], y, TB_[3], ES[3]);
            fin_gather_k<64, 64><<<cdiv(n, 4), TB, 0, stream>>>(bufB, Rp[6], Bp[6], off, y, bufA, n);
            mfma_conv<64, 64><<<MT[3] / 2, TB, 0, stream>>>(
                bufA, src[3], pseudo[3], pack, tileOf, pos, Wtb + WT_OFF[6], y, TB_[3], ES[3]);
            fin_pool_k<64, 64><<<NS[4], TB, 0, stream>>>(
                bufA, Rp[7], Bp[7], off, y, clist + NODE_OFF[3], bufB, NS[3]);
        }
        head_kernel<<<1, 64, 0, stream>>>(bufB, fc1w, fc1b, fc2w, fc2b, outp);
    } else if (ws_size >= fallbackNeed) {
        // ---------------- legacy edge-centric fallback ---------------------
        float* h0 = bufA;
        float* h1 = bufB;
        float* deg = (float*)degi;
        for (int l = 0; l < 4; ++l) {
            int E = ES[l], n = NS[l];
            (void)hipMemsetAsync(deg, 0, n * 4, stream);
            deg_kernel<<<cdiv(E, TB), TB, 0, stream>>>(dst[l], deg, E);
            for (int cc = 0; cc < 2; ++cc) {
                int li = (l == 0) ? cc : 2 * l + cc;
                if (l == 0 && cc == 0) {
                    (void)hipMemsetAsync(h0, 0, (size_t)n * 32 * 4, stream);
                    conv1_fused<<<cdiv(E, 8), TB, 0, stream>>>(x, src[0], dst[0], pseudo[0], Wp[0], h0, E);
                    finalize_k<1, 32><<<cdiv(n, 8), TB, 0, stream>>>(x, Rp[0], Bp[0], deg, h0, n);
                } else {
                    int ic = (l == 0) ? 32 : ((l == 1 && cc == 0) ? 32 : 64);
                    int oc = (l == 0) ? 32 : 64;
                    (void)hipMemsetAsync(h1, 0, (size_t)n * oc * 4, stream);
                    if (ic == 32 && oc == 32) {
                        conv_edges_inline<32, 32><<<cdiv(E, 8), TB, 0, stream>>>(h0, src[l], dst[l], pseudo[l], Wp[li], h1, E);
                        finalize_k<32, 32><<<cdiv(n, 8), TB, 0, stream>>>(h0, Rp[li], Bp[li], deg, h1, n);
                    } else if (ic == 32) {
                        conv_edges_inline<32, 64><<<cdiv(E, 4), TB, 0, stream>>>(h0, src[l], dst[l], pseudo[l], Wp[li], h1, E);
                        finalize_k<32, 64><<<cdiv(n, 4), TB, 0, stream>>>(h0, Rp[li], Bp[li], deg, h1, n);
                    } else {
                        conv_edges_inline<64, 64><<<cdiv(E, 4), TB, 0, stream>>>(h0, src[l], dst[l], pseudo[l], Wp[li], h1, E);
                        finalize_k<64, 64><<<cdiv(n, 4), TB, 0, stream>>>(h0, Rp[li], Bp[li], deg, h1, n);
                    }
                    float* tmp = h0; h0 = h1; h1 = tmp;
                }
            }
            int oc = (l == 0) ? 32 : 64;
            int logC = (l == 0) ? 5 : 6;
            (void)hipMemsetAsync(pool, 0, (size_t)NS[l + 1] * oc * 4, stream);
            pool_scatter<<<cdiv(n * oc, TB), TB, 0, stream>>>(h0, cluster[l], pool, n, logC);
            pool_decode<<<cdiv(NS[l + 1] * oc, TB), TB, 0, stream>>>(pool, h1, NS[l + 1] * oc);
            float* tmp = h0; h0 = h1; h1 = tmp;
        }
        head_kernel<<<1, 64, 0, stream>>>(h0, fc1w, fc1b, fc2w, fc2b, outp);
    }
}

// Round 11
// 385.678 us; speedup vs baseline: 1.1280x; 1.1280x over previous
//
#include <hip/hip_runtime.h>
#include <hip/hip_bf16.h>

#define KS 5
#define K3 125

typedef __attribute__((ext_vector_type(8))) short short8;
typedef __attribute__((ext_vector_type(4))) float floatx4;

__device__ inline unsigned enc_f(float f) {
    int b = __float_as_int(f);
    return (b >= 0) ? ((unsigned)b | 0x80000000u) : ~((unsigned)b);
}

__device__ inline unsigned short f2bf(float f) {
    unsigned u = __float_as_uint(f);
    u += 0x7FFFu + ((u >> 16) & 1u);  // RNE
    return (unsigned short)(u >> 16);
}
__device__ inline float bf2f(unsigned short h) {
    return __uint_as_float((unsigned)h << 16);
}
__device__ inline unsigned pack2bf(float a, float b) {
    return (unsigned)f2bf(a) | ((unsigned)f2bf(b) << 16);
}

// ---------------------------------------------------------------------------
// Inline basis helpers
// ---------------------------------------------------------------------------
__device__ inline void edge_basis(const float* __restrict__ pseudo, int e,
                                  float* bs, int* ks) {
    float fr[3];
    int bot[3];
#pragma unroll
    for (int d = 0; d < 3; ++d) {
        float v = pseudo[e * 3 + d] * (float)(KS - 1);
        float fl = fminf(floorf(v), (float)(KS - 2));
        fr[d] = v - fl;
        bot[d] = (int)fl;
    }
    const int strides[3] = {1, KS, KS * KS};
#pragma unroll
    for (int s = 0; s < 8; ++s) {
        float b = 1.f;
        int w = 0;
#pragma unroll
        for (int d = 0; d < 3; ++d) {
            int bit = (s >> d) & 1;
            b *= bit ? fr[d] : (1.f - fr[d]);
            w += (bot[d] + bit) * strides[d];
        }
        bs[s] = b;
        ks[s] = w;
    }
}

__device__ inline void edge_fracs(const float* __restrict__ pseudo, int e, float* bs) {
    float fr[3];
#pragma unroll
    for (int d = 0; d < 3; ++d) {
        float v = pseudo[e * 3 + d] * (float)(KS - 1);
        float fl = fminf(floorf(v), (float)(KS - 2));
        fr[d] = v - fl;
    }
#pragma unroll
    for (int s = 0; s < 8; ++s) {
        float b = 1.f;
#pragma unroll
        for (int d = 0; d < 3; ++d) b *= ((s >> d) & 1) ? fr[d] : (1.f - fr[d]);
        bs[s] = b;
    }
}

__device__ inline int edge_bucket(const float* __restrict__ pseudo, int e) {
    int kb = 0;
#pragma unroll
    for (int d = 0; d < 3; ++d) {
        float v = pseudo[e * 3 + d] * (float)(KS - 1);
        int fl = (int)fminf(floorf(v), (float)(KS - 2));
        kb += fl << (2 * d);
    }
    return kb;
}

// ---------------------------------------------------------------------------
// Pre-pass 1 (merged): hist partials + degree (blocks 0..679)
// + cluster member lists (blocks 680..764)
// + weight transpose-convert via LDS (blocks 765..1639, one per k-slice).
// degi atomicAdd's return value = edge rank within dst (stored to posArr).
// ---------------------------------------------------------------------------
__global__ __launch_bounds__(256) void pre1(
    const float* __restrict__ p0, const float* __restrict__ p1,
    const float* __restrict__ p2, const float* __restrict__ p3,
    const int* __restrict__ d0, const int* __restrict__ d1,
    const int* __restrict__ d2, const int* __restrict__ d3,
    const int* __restrict__ c0, const int* __restrict__ c1,
    const int* __restrict__ c2, const int* __restrict__ c3,
    const float* __restrict__ w12, const float* __restrict__ w2,
    const float* __restrict__ w3, const float* __restrict__ w4,
    const float* __restrict__ w5, const float* __restrict__ w6,
    const float* __restrict__ w7,
    int* __restrict__ hpart, int* __restrict__ degi,
    int* __restrict__ ccnt, int* __restrict__ clist,
    short* __restrict__ Wt, int* __restrict__ posArr) {
    __shared__ float wls[64 * 65];  // 16.6 KB transpose buffer (wcvt blocks)
    __shared__ int h[64];
    int b = blockIdx.x;
    int t = threadIdx.x;
    if (b >= 765) {  // ---- wcvt: one block per (tensor, k) slice ----
        int sl = b - 765;
        const float* srcp;
        int IC, OC, lgI, lgO, per;
        size_t obase;
        if (sl < 125) {
            IC = 32; OC = 32; lgI = 5; lgO = 5; per = 1024;
            srcp = w12 + (size_t)sl * 1024;
            obase = (size_t)sl * 1024;
        } else if (sl < 250) {
            int k = sl - 125;
            IC = 32; OC = 64; lgI = 5; lgO = 6; per = 2048;
            srcp = w2 + (size_t)k * 2048;
            obase = 128000 + (size_t)k * 2048;
        } else {
            int q = sl - 250;
            int ts = q / 125;
            int k = q - ts * 125;
            const float* Ws[5] = {w3, w4, w5, w6, w7};
            IC = 64; OC = 64; lgI = 6; lgO = 6; per = 4096;
            srcp = Ws[ts] + (size_t)k * 4096;
            obase = 384000 + (size_t)ts * 512000 + (size_t)k * 4096;
        }
        for (int r = t; r < per; r += 256) {  // coalesced fp32 load
            int i = r >> lgO, o = r & (OC - 1);
            wls[i * (OC + 1) + o] = srcp[r];
        }
        __syncthreads();
        for (int j = t; j < per; j += 256) {  // coalesced bf16 store
            int o = j >> lgI, i = j & (IC - 1);
            Wt[obase + j] = (short)f2bf(wls[i * (OC + 1) + o]);
        }
        return;
    }
    if (b >= 680) {  // ---- clist part ----
        int idx = (b - 680) * 256 + t;
        int j, cof, nof;
        const int* cl;
        if (idx < 16384)      { j = idx;         cl = c0; cof = 0;    nof = 0; }
        else if (idx < 20480) { j = idx - 16384; cl = c1; cof = 4096; nof = 16384; }
        else if (idx < 21504) { j = idx - 20480; cl = c2; cof = 5120; nof = 20480; }
        else if (idx < 21760) { j = idx - 21504; cl = c3; cof = 5376; nof = 21504; }
        else return;
        int c = cl[j];
        int slot = atomicAdd(&ccnt[cof + c], 1) & 3;  // defensive: slot < 4
        clist[nof + c * 4 + slot] = j;
        return;
    }
    // ---- hist + degree part (block b == hist row b) ----
    int l, lb, E, dof, eof_;
    const float* ps;
    const int* ds;
    if (b < 512)      { l = 0; lb = b;       ps = p0; ds = d0; E = 131072; dof = 0;     eof_ = 0; }
    else if (b < 640) { l = 1; lb = b - 512; ps = p1; ds = d1; E = 32768;  dof = 16384; eof_ = 131072; }
    else if (b < 672) { l = 2; lb = b - 640; ps = p2; ds = d2; E = 8192;   dof = 20480; eof_ = 163840; }
    else              { l = 3; lb = b - 672; ps = p3; ds = d3; E = 2048;   dof = 21504; eof_ = 172032; }
    if (t < 64) h[t] = 0;
    __syncthreads();
    int e = lb * 256 + t;
    if (e < E) {
        atomicAdd(&h[edge_bucket(ps, e)], 1);
        int rel = atomicAdd(&degi[dof + ds[e]], 1);  // rank within dst = free
        posArr[eof_ + e] = rel;
    }
    __syncthreads();
    if (t < 64) hpart[b * 64 + t] = h[t];  // unconditional: full row written
}

// ---------------------------------------------------------------------------
// Pre-pass 2 (merged): CSR scan + tile layout + parallel bbase. (verified R5)
// ---------------------------------------------------------------------------
__global__ __launch_bounds__(1024) void pre2(const int* __restrict__ hpart,
                                             int* __restrict__ bbase,
                                             int* __restrict__ tileOf,
                                             int* __restrict__ pack,
                                             const int* __restrict__ degi,
                                             int* __restrict__ off) {
    int b = blockIdx.x;
    int t = threadIdx.x;
    __shared__ int ls[1024];
    __shared__ int aux[192];
    if (b < 4) {  // ---- CSR scan ----
        const int Nv[4] = {16384, 4096, 1024, 256};
        const int DOFv[4] = {0, 16384, 20480, 21504};
        const int OFFv[4] = {0, 16385, 20482, 21507};
        int l = b;
        int n = Nv[l];
        const int* d = degi + DOFv[l];
        int* o = off + OFFv[l];
        int per = (n + 1023) >> 10;
        int beg = t * per;
        int end = (beg + per < n) ? beg + per : n;
        int s = 0;
        for (int j = beg; j < end; ++j) s += d[j];
        ls[t] = s;
        __syncthreads();
        for (int dd = 1; dd < 1024; dd <<= 1) {
            int v = (t >= dd) ? ls[t - dd] : 0;
            __syncthreads();
            ls[t] += v;
            __syncthreads();
        }
        int base = (t == 0) ? 0 : ls[t - 1];
        for (int j = beg; j < end; ++j) {
            o[j] = base;
            base += d[j];
        }
        if (t == 1023) o[n] = ls[1023];
    } else {  // ---- tile layout + per-row bases (parallel) ----
        const int TBv[4] = {0, 2112, 2688, 2880};
        const int MTv[4] = {2112, 576, 192, 96};
        const int HBv[4] = {0, 512, 640, 672};
        const int NBv[4] = {512, 128, 32, 8};
        int l = b - 4;
        int tileBase = TBv[l];
        int hb = HBv[l], nb = NBv[l];
        int bucket = t & 63, seg = t >> 6;
        int rps = (nb + 15) >> 4;
        int r0 = seg * rps;
        int r1 = r0 + rps;
        if (r1 > nb) r1 = nb;
        int ssum = 0;
        for (int lb = r0; lb < r1; ++lb) ssum += hpart[(hb + lb) * 64 + bucket];
        ls[seg * 64 + bucket] = ssum;
        __syncthreads();
        int pre = 0;
        for (int s2 = 0; s2 < seg; ++s2) pre += ls[s2 * 64 + bucket];
        if (seg == 15) aux[bucket] = pre + ssum;
        __syncthreads();
        if (t < 64) aux[64 + t] = (aux[t] + 63) >> 6;
        __syncthreads();
        for (int d = 1; d < 64; d <<= 1) {
            int v = 0;
            if (t < 64 && t >= d) v = aux[64 + t - d];
            __syncthreads();
            if (t < 64) aux[64 + t] += v;
            __syncthreads();
        }
        if (t < 64) {
            int cnt = aux[t];
            int tiles = (cnt + 63) >> 6;
            int tb = tileBase + aux[64 + t] - tiles;
            int gstart = tb * 64;
            aux[128 + t] = gstart;
            for (int q = 0; q < tiles; ++q) tileOf[tb + q] = t;
            for (int idx = gstart + cnt; idx < (tb + tiles) * 64; ++idx) pack[idx] = -1;
            if (t == 63) {
                for (int q = tileBase + aux[64 + 63]; q < tileBase + MTv[l]; ++q)
                    tileOf[q] = -1;
            }
        }
        __syncthreads();
        int run = aux[128 + bucket] + pre;
        for (int lb = r0; lb < r1; ++lb) {
            bbase[(hb + lb) * 64 + bucket] = run;
            run += hpart[(hb + lb) * 64 + bucket];
        }
    }
}

// ---------------------------------------------------------------------------
// Pre-pass 3: counting sort (zero global atomics — bucket bases from bbase,
// absolute pos = csr[dst] + rel-rank from pre1).
// ---------------------------------------------------------------------------
__global__ __launch_bounds__(256) void scatter_pos_all(
    const float* __restrict__ p0, const float* __restrict__ p1,
    const float* __restrict__ p2, const float* __restrict__ p3,
    const int* __restrict__ d0, const int* __restrict__ d1,
    const int* __restrict__ d2, const int* __restrict__ d3,
    const int* __restrict__ bbase, const int* __restrict__ csr,
    int* __restrict__ pack, int* __restrict__ posArr,
    int* __restrict__ esrt) {
    int b = blockIdx.x;
    int l, lb, E, eof_, cof;
    const float* ps;
    const int* ds;
    if (b < 512)      { l = 0; lb = b;       ps = p0; ds = d0; E = 131072; eof_ = 0;      cof = 0; }
    else if (b < 640) { l = 1; lb = b - 512; ps = p1; ds = d1; E = 32768;  eof_ = 131072; cof = 16385; }
    else if (b < 672) { l = 2; lb = b - 640; ps = p2; ds = d2; E = 8192;   eof_ = 163840; cof = 20482; }
    else              { l = 3; lb = b - 672; ps = p3; ds = d3; E = 2048;   eof_ = 172032; cof = 21507; }
    const int* csrL = csr + cof;
    __shared__ int h[64], lbk[64], gb[64], sh[64];
    __shared__ int sp[256];
    __shared__ unsigned char skk[256];
    int t = threadIdx.x;
    int e = lb * 256 + t;
    int kb = -1;
    if (t < 64) {
        h[t] = 0;
        gb[t] = bbase[b * 64 + t];
    }
    __syncthreads();
    if (e < E) {
        kb = edge_bucket(ps, e);
        atomicAdd(&h[kb], 1);
        int p = csrL[ds[e]] + posArr[eof_ + e];  // absolute pos, no atomic
        posArr[eof_ + e] = p;
        if (l == 0 && p >= 0 && p < 131072) esrt[p] = e;
    }
    __syncthreads();
    if (t < 64) sh[t] = h[t];
    __syncthreads();
    for (int d = 1; d < 64; d <<= 1) {
        int v = (t < 64 && t >= d) ? sh[t - d] : 0;
        __syncthreads();
        if (t < 64) sh[t] += v;
        __syncthreads();
    }
    if (t < 64) {
        lbk[t] = sh[t] - h[t];
        h[t] = 0;
    }
    __syncthreads();
    if (kb >= 0) {
        int ppos = lbk[kb] + atomicAdd(&h[kb], 1);
        sp[ppos] = e;
        skk[ppos] = (unsigned char)kb;
    }
    __syncthreads();
    int Pb = E - lb * 256;
    if (Pb > 256) Pb = 256;
    if (t < Pb) {
        int k = skk[t];
        pack[gb[k] + (t - lbk[k])] = sp[t];
    }
}

// ---------------------------------------------------------------------------
// Fused conv1 (in_c = 1) + finalize with 1-ahead software pipeline (R9).
// ---------------------------------------------------------------------------
__global__ __launch_bounds__(256) void conv1_fin(
    const float* __restrict__ x, const int* __restrict__ src,
    const float* __restrict__ pseudo, const int* __restrict__ esrt,
    const int* __restrict__ off, const float* __restrict__ W,
    const float* __restrict__ R, const float* __restrict__ B,
    float* __restrict__ out, int n, int Emax) {
    const int lane = threadIdx.x & 63;
    const int wid = threadIdx.x >> 6;
    const int sub = lane >> 5;
    const int o = lane & 31;
    int j = (blockIdx.x * 4 + wid) * 2 + sub;
    if (j >= n) return;
    int b0 = off[j], b1 = off[j + 1];
    if (b0 < 0) b0 = 0;
    if (b1 > Emax) b1 = Emax;
    float acc = 0.f;
    float px = 0.f, py = 0.f, pz = 0.f, xs = 0.f;
    if (b0 < b1) {
        int e0 = esrt[b0];
        px = pseudo[e0 * 3];
        py = pseudo[e0 * 3 + 1];
        pz = pseudo[e0 * 3 + 2];
        xs = x[src[e0]];
    }
    for (int r = b0; r < b1; ++r) {
        float cpx = px, cpy = py, cpz = pz, cxs = xs;
        if (r + 1 < b1) {  // prefetch next edge's operands
            int e1 = esrt[r + 1];
            px = pseudo[e1 * 3];
            py = pseudo[e1 * 3 + 1];
            pz = pseudo[e1 * 3 + 2];
            xs = x[src[e1]];
        }
        float fr[3];
        int bot[3];
        float pv[3] = {cpx, cpy, cpz};
#pragma unroll
        for (int d = 0; d < 3; ++d) {
            float v = pv[d] * (float)(KS - 1);
            float fl = fminf(floorf(v), (float)(KS - 2));
            fr[d] = v - fl;
            bot[d] = (int)fl;
        }
        const int strides[3] = {1, KS, KS * KS};
        float w = 0.f;
#pragma unroll
        for (int s = 0; s < 8; ++s) {
            float bsv = 1.f;
            int wk = 0;
#pragma unroll
            for (int d = 0; d < 3; ++d) {
                int bit = (s >> d) & 1;
                bsv *= bit ? fr[d] : (1.f - fr[d]);
                wk += (bot[d] + bit) * strides[d];
            }
            w = fmaf(bsv, W[wk * 32 + o], w);
        }
        acc = fmaf(w, cxs, acc);
    }
    float d = fmaxf((float)(b1 - b0), 1.f);
    float v = acc / d + x[j] * R[o] + B[o];
    out[(size_t)j * 32 + o] = (v > 0.f) ? v : expm1f(v);
}

// ---------------------------------------------------------------------------
// MFMA bucket-tile conv, phased staging (R8/R9 structure, verified; R10's
// 2-tile pipeline regressed +44 us — compiler won't hoist staging across
// __syncthreads, so it only doubled LDS/VGPR. Reverted.)
// ---------------------------------------------------------------------------
template <int IN_C, int OUT_C>
__global__ __launch_bounds__(256, 6) void mfma_conv(
    const float* __restrict__ x, const int* __restrict__ src,
    const float* __restrict__ pseudo, const int* __restrict__ pack,
    const int* __restrict__ tileOf, const int* __restrict__ pos,
    const short* __restrict__ Wt, unsigned short* __restrict__ y, int tileBase,
    int Emax) {
    constexpr int PH = (IN_C == 64) ? 4 : 2;  // staging phases
    constexpr int SPP = 8 / PH;               // slots per phase
    constexpr int KPH = SPP * IN_C;           // K per phase (=128)
    constexpr int KP = KPH + 8;               // padded row (shorts) = 136
    constexpr int NT = OUT_C / 16;
    constexpr int IP = IN_C / 4;
    __shared__ short As[64 * KP];             // 17.4 KB
    __shared__ int posL[64];
    const int tid = threadIdx.x;
    int t = tileBase + blockIdx.x;
    int kb = tileOf[t];
    if (kb < 0 || kb >= 64) return;  // block-uniform
    kb = __builtin_amdgcn_readfirstlane(kb);
    const int kbase = (kb & 3) + 5 * ((kb >> 2) & 3) + 25 * ((kb >> 4) & 3);
    const int eLoc = tid >> 2, part = tid & 3;
    int e = pack[t * 64 + eLoc];
    if (e >= Emax) e = -1;  // defensive
    float bs[8];
    float4 xq[IP / 4];
    if (e >= 0) edge_fracs(pseudo, e, bs);
    else {
#pragma unroll
        for (int s = 0; s < 8; ++s) bs[s] = 0.f;
    }
    if (part == 0) posL[eLoc] = (e >= 0) ? pos[e] : -1;
#pragma unroll
    for (int g = 0; g < IP / 4; ++g)
        xq[g] = (e >= 0)
                    ? *(const float4*)(x + (size_t)src[e] * IN_C + part * IP + g * 4)
                    : make_float4(0.f, 0.f, 0.f, 0.f);
    const int wave = tid >> 6, lane = tid & 63;
    const int quad = lane >> 4, lm = lane & 15;
    floatx4 acc[NT];
#pragma unroll
    for (int nt = 0; nt < NT; ++nt) acc[nt] = (floatx4){0.f, 0.f, 0.f, 0.f};
    const short* myrow = &As[(wave * 16 + lm) * KP];
#pragma unroll
    for (int ph = 0; ph < PH; ++ph) {
        if (ph) __syncthreads();  // drain previous phase's MFMA reads
        // ---- stage slots [ph*SPP, ph*SPP+SPP) ----
#pragma unroll
        for (int s2 = 0; s2 < SPP; ++s2) {
            const float b = bs[ph * SPP + s2];
            short* rowp = &As[eLoc * KP + s2 * IN_C + part * IP];
#pragma unroll
            for (int g = 0; g < IP / 4; ++g) {
                unsigned lo = pack2bf(b * xq[g].x, b * xq[g].y);
                unsigned hi = pack2bf(b * xq[g].z, b * xq[g].w);
                *(uint2*)(rowp + 4 * g) = make_uint2(lo, hi);
            }
        }
        __syncthreads();
        // ---- MFMA over this phase's K ----
#pragma unroll
        for (int kstep = 0; kstep < KPH / 32; ++kstep) {
            const int kg = kstep * 32;
            const int s2 = kg / IN_C;
            const int i0 = kg % IN_C;
            const int s = ph * SPP + s2;
            const int ks = kbase + (s & 1) + 5 * ((s >> 1) & 1) + 25 * ((s >> 2) & 1);
            short8 a = *(const short8*)&myrow[kg + quad * 8];
#pragma unroll
            for (int nt = 0; nt < NT; ++nt) {
                const short* bp =
                    Wt + ((size_t)ks * OUT_C + nt * 16 + lm) * IN_C + i0 + quad * 8;
                short8 bfr = *(const short8*)bp;
                acc[nt] = __builtin_amdgcn_mfma_f32_16x16x32_bf16(a, bfr, acc[nt], 0, 0, 0);
            }
        }
    }
#pragma unroll
    for (int nt = 0; nt < NT; ++nt) {
#pragma unroll
        for (int r = 0; r < 4; ++r) {
            int row = wave * 16 + quad * 4 + r;
            int p = posL[row];
            if (p >= 0 && p < Emax) y[(size_t)p * OUT_C + nt * 16 + lm] = f2bf(acc[nt][r]);
        }
    }
}

// ---------------------------------------------------------------------------
// Finalize (gather): out = (sum of dst's CSR run of bf16 y)/deg + x@R + B, ELU.
// ---------------------------------------------------------------------------
template <int OUT_C>
__device__ inline float csr_sum(const int* __restrict__ off,
                                const unsigned short* __restrict__ y, int j, int o,
                                float& dcount) {
    int b0 = off[j], b1 = off[j + 1];
    if (b0 < 0) b0 = 0;
    if (b1 < b0) b1 = b0;
    dcount = fmaxf((float)(b1 - b0), 1.f);
    float s0 = 0.f, s1 = 0.f, s2 = 0.f, s3 = 0.f;
    int r = b0;
    for (; r + 4 <= b1; r += 4) {
        s0 += bf2f(y[(size_t)(r + 0) * OUT_C + o]);
        s1 += bf2f(y[(size_t)(r + 1) * OUT_C + o]);
        s2 += bf2f(y[(size_t)(r + 2) * OUT_C + o]);
        s3 += bf2f(y[(size_t)(r + 3) * OUT_C + o]);
    }
    for (; r < b1; ++r) s0 += bf2f(y[(size_t)r * OUT_C + o]);
    return (s0 + s1) + (s2 + s3);
}

template <int IN_C, int OUT_C>
__global__ __launch_bounds__(256) void fin_gather_k(
    const float* __restrict__ xin, const float* __restrict__ R,
    const float* __restrict__ B, const int* __restrict__ off,
    const unsigned short* __restrict__ y, float* __restrict__ out, int n) {
    const int lane = threadIdx.x & 63;
    const int wid = threadIdx.x >> 6;
    constexpr int EPW = 64 / OUT_C;
    const int sub = (EPW == 2) ? (lane >> 5) : 0;
    const int o = lane & (OUT_C - 1);
    int j = (blockIdx.x * (blockDim.x >> 6) + wid) * EPW + sub;
    if (j >= n) return;
    float xv = (o < IN_C) ? xin[j * IN_C + o] : 0.f;
    float acc = B[o];
#pragma unroll 4
    for (int i = 0; i < IN_C; ++i) {
        float xi = __shfl(xv, i, OUT_C);
        acc = fmaf(xi, R[i * OUT_C + o], acc);
    }
    float d;
    float s = csr_sum<OUT_C>(off, y, j, o, d);
    float v = s / d + acc;
    out[j * OUT_C + o] = (v > 0.f) ? v : expm1f(v);
}

// ---------------------------------------------------------------------------
// Fused finalize + pool-max: every cluster has exactly 4 members (clist).
// ---------------------------------------------------------------------------
template <int IN_C, int OUT_C>
__global__ __launch_bounds__(256) void fin_pool_k(
    const float* __restrict__ xin, const float* __restrict__ R,
    const float* __restrict__ B, const int* __restrict__ off,
    const unsigned short* __restrict__ y, const int* __restrict__ clist,
    float* __restrict__ out, int nsrc) {
    constexpr int CPB = 256 / (4 * OUT_C);
    const int t = threadIdx.x;
    const int o = t & (OUT_C - 1);
    const int mem = (t / OUT_C) & 3;
    const int g = t / (4 * OUT_C);
    const int c = blockIdx.x * CPB + g;
    int j = clist[c * 4 + mem];
    if (j < 0) j = 0;
    if (j >= nsrc) j = nsrc - 1;  // defensive
    float xv = (o < IN_C) ? xin[(size_t)j * IN_C + o] : 0.f;
    float acc = B[o];
#pragma unroll 4
    for (int i = 0; i < IN_C; ++i) {
        float xi = __shfl(xv, i, OUT_C);
        acc = fmaf(xi, R[i * OUT_C + o], acc);
    }
    float d;
    float s = csr_sum<OUT_C>(off, y, j, o, d);
    float v = s / d + acc;
    v = (v > 0.f) ? v : expm1f(v);
    __shared__ float sh[256];
    sh[t] = v;
    __syncthreads();
    if (mem == 0) {
        const float* base = &sh[g * 4 * OUT_C];
        float r01 = fmaxf(base[o], base[OUT_C + o]);
        float r23 = fmaxf(base[2 * OUT_C + o], base[3 * OUT_C + o]);
        out[(size_t)c * OUT_C + o] = fmaxf(r01, r23);
    }
}

// ---------------------------------------------------------------------------
// Fallback kernels (small-ws path only).
// ---------------------------------------------------------------------------
__global__ __launch_bounds__(256) void conv1_fused(const float* __restrict__ x,
                                                   const int* __restrict__ src,
                                                   const int* __restrict__ dst,
                                                   const float* __restrict__ pseudo,
                                                   const float* __restrict__ W,
                                                   float* __restrict__ out, int E) {
    const int lane = threadIdx.x & 63;
    const int wid = threadIdx.x >> 6;
    const int sub = lane >> 5;
    const int o = lane & 31;
    int e = (blockIdx.x * 4 + wid) * 2 + sub;
    if (e >= E) return;
    float bs[8];
    int ks[8];
    edge_basis(pseudo, e, bs, ks);
    float acc = 0.f;
#pragma unroll
    for (int s = 0; s < 8; ++s) acc = fmaf(bs[s], W[ks[s] * 32 + o], acc);
    atomicAdd(&out[(size_t)dst[e] * 32 + o], acc * x[src[e]]);
}

template <int IN_C, int OUT_C>
__global__ __launch_bounds__(256) void conv_edges_inline(
    const float* __restrict__ x, const int* __restrict__ src,
    const int* __restrict__ dst, const float* __restrict__ pseudo,
    const float* __restrict__ W, float* __restrict__ out, int E) {
    const int lane = threadIdx.x & 63;
    const int wid = threadIdx.x >> 6;
    constexpr int EPW = 64 / OUT_C;
    const int sub = (EPW == 2) ? (lane >> 5) : 0;
    const int o = lane & (OUT_C - 1);
    long e = (long)(blockIdx.x * (blockDim.x >> 6) + wid) * EPW + sub;
    if (e >= E) return;
    float bs[8];
    int ks[8];
    edge_basis(pseudo, e, bs, ks);
    const int s_ = src[e];
    const int d_ = dst[e];
    float xv = (o < IN_C) ? x[s_ * IN_C + o] : 0.f;
    float acc = 0.f;
#pragma unroll
    for (int s = 0; s < 8; ++s) {
        const float b = bs[s];
        const float* Wk = W + (long)ks[s] * IN_C * OUT_C;
#pragma unroll 4
        for (int i = 0; i < IN_C; ++i) {
            float xi = __shfl(xv, i, OUT_C);
            acc = fmaf(b * xi, Wk[i * OUT_C + o], acc);
        }
    }
    atomicAdd(&out[(long)d_ * OUT_C + o], acc);
}

__global__ void deg_kernel(const int* __restrict__ dst, float* __restrict__ deg, int E) {
    int e = blockIdx.x * blockDim.x + threadIdx.x;
    if (e >= E) return;
    atomicAdd(&deg[dst[e]], 1.0f);
}

template <int IN_C, int OUT_C>
__global__ __launch_bounds__(256) void finalize_k(
    const float* __restrict__ xin, const float* __restrict__ R,
    const float* __restrict__ B, const float* __restrict__ deg,
    float* __restrict__ out, int n) {
    const int lane = threadIdx.x & 63;
    const int wid = threadIdx.x >> 6;
    constexpr int EPW = 64 / OUT_C;
    const int sub = (EPW == 2) ? (lane >> 5) : 0;
    const int o = lane & (OUT_C - 1);
    int j = (blockIdx.x * (blockDim.x >> 6) + wid) * EPW + sub;
    if (j >= n) return;
    float xv = (o < IN_C) ? xin[j * IN_C + o] : 0.f;
    float acc = B[o];
#pragma unroll 4
    for (int i = 0; i < IN_C; ++i) {
        float xi = __shfl(xv, i, OUT_C);
        acc = fmaf(xi, R[i * OUT_C + o], acc);
    }
    float d = fmaxf(deg[j], 1.f);
    float v = out[j * OUT_C + o] / d + acc;
    out[j * OUT_C + o] = (v > 0.f) ? v : expm1f(v);
}

__global__ void pool_scatter(const float* __restrict__ h, const int* __restrict__ cluster,
                             unsigned* __restrict__ pool, int n, int logC) {
    int idx = blockIdx.x * blockDim.x + threadIdx.x;
    if (idx >= (n << logC)) return;
    int j = idx >> logC;
    int c = idx & ((1 << logC) - 1);
    atomicMax(&pool[(cluster[j] << logC) + c], enc_f(h[idx]));
}

__global__ void pool_decode(const unsigned* __restrict__ pool, float* __restrict__ out, int total) {
    int idx = blockIdx.x * blockDim.x + threadIdx.x;
    if (idx >= total) return;
    unsigned u = pool[idx];
    int b = (u & 0x80000000u) ? (int)(u & 0x7FFFFFFFu) : (int)(~u);
    out[idx] = __int_as_float(b);
}

// ---------------------------------------------------------------------------
// Head: mean(64x64) -> fc1 -> fc2 -> log_softmax
// ---------------------------------------------------------------------------
__global__ void head_kernel(const float* __restrict__ h, const float* __restrict__ fc1w,
                            const float* __restrict__ fc1b, const float* __restrict__ fc2w,
                            const float* __restrict__ fc2b, float* __restrict__ out) {
    __shared__ float m[64], t[64], u[10];
    int lane = threadIdx.x;
    float s = 0.f;
    for (int j = 0; j < 64; ++j) s += h[j * 64 + lane];
    m[lane] = s * (1.f / 64.f);
    __syncthreads();
    float a = fc1b[lane];
    for (int i = 0; i < 64; ++i) a = fmaf(m[i], fc1w[i * 64 + lane], a);
    t[lane] = a;
    __syncthreads();
    if (lane < 10) {
        float b = fc2b[lane];
        for (int i = 0; i < 64; ++i) b = fmaf(t[i], fc2w[i * 10 + lane], b);
        u[lane] = b;
    }
    __syncthreads();
    if (lane < 10) {
        float mx = u[0];
        for (int i = 1; i < 10; ++i) mx = fmaxf(mx, u[i]);
        float se = 0.f;
        for (int i = 0; i < 10; ++i) se += expf(u[i] - mx);
        out[lane] = u[lane] - mx - logf(se);
    }
}

// ---------------------------------------------------------------------------
// Host side
// ---------------------------------------------------------------------------
static inline int cdiv(int a, int b) { return (a + b - 1) / b; }

extern "C" void kernel_launch(void* const* d_in, const int* in_sizes, int n_in,
                              void* d_out, int out_size, void* d_ws, size_t ws_size,
                              hipStream_t stream) {
    const float* x = (const float*)d_in[0];
    const int* src[4] = {(const int*)d_in[1], (const int*)d_in[5], (const int*)d_in[9], (const int*)d_in[13]};
    const int* dst[4] = {(const int*)d_in[2], (const int*)d_in[6], (const int*)d_in[10], (const int*)d_in[14]};
    const float* pseudo[4] = {(const float*)d_in[3], (const float*)d_in[7], (const float*)d_in[11], (const float*)d_in[15]};
    const int* cluster[4] = {(const int*)d_in[4], (const int*)d_in[8], (const int*)d_in[12], (const int*)d_in[16]};
    const float* Wp[8], *Rp[8], *Bp[8];
    for (int l = 0; l < 8; ++l) {
        Wp[l] = (const float*)d_in[17 + 3 * l];
        Rp[l] = (const float*)d_in[18 + 3 * l];
        Bp[l] = (const float*)d_in[19 + 3 * l];
    }
    const float* fc1w = (const float*)d_in[41];
    const float* fc1b = (const float*)d_in[42];
    const float* fc2w = (const float*)d_in[43];
    const float* fc2b = (const float*)d_in[44];
    float* outp = (float*)d_out;

    const int NS[5] = {16384, 4096, 1024, 256, 64};
    const int ES[4] = {16384 * 8, 4096 * 8, 1024 * 8, 256 * 8};
    const int MT[4] = {2048 + 64, 512 + 64, 128 + 64, 32 + 64};
    const int TB_[4] = {0, 2112, 2112 + 576, 2112 + 576 + 192};
    const int TOT_TILES = 2112 + 576 + 192 + 96;  // 2976
    const int DTOT = 21760;
    const int OFF2[4] = {0, 16385, 20482, 21507};
    const int OFFTOT = 21764;
    const int EBASE[4] = {0, 131072, 163840, 172032};
    const int ETOT = 174080;
    const int NODE_OFF[4] = {0, 16384, 20480, 21504};
    const int CCTOT = 4096 + 1024 + 256 + 64;  // 5440
    const int HTOT = 680;
    const int WT_OFF[7] = {0, 128000, 384000, 896000, 1408000, 1920000, 2432000};
    const int WT_TOT = 2944000;
    const int NSLICE = 875;  // 125 + 125 + 5*125 weight k-slices

    char* w = (char*)d_ws;
    auto take = [&](size_t bytes) -> char* {
        char* r = w;
        w += (bytes + 255) & ~(size_t)255;
        return r;
    };
    float* bufA = (float*)take((size_t)NS[0] * 64 * 4);
    float* bufB = (float*)take((size_t)NS[0] * 64 * 4);
    unsigned* pool = (unsigned*)take((size_t)NS[1] * 64 * 4);  // fallback only
    // ---- contiguous zero-init region: ccnt | degi ----
    char* zbase = w;
    int* ccnt = (int*)take((size_t)CCTOT * 4);
    int* degi = (int*)take((size_t)DTOT * 4);
    size_t zbytes = (size_t)(w - zbase);
    size_t fallbackNeed = (size_t)(w - (char*)d_ws);
    int* tileOf = (int*)take((size_t)TOT_TILES * 4);
    int* hpart = (int*)take((size_t)HTOT * 64 * 4);
    int* bbase = (int*)take((size_t)HTOT * 64 * 4);
    int* pack = (int*)take((size_t)TOT_TILES * 64 * 4);
    int* csr = (int*)take((size_t)OFFTOT * 4);
    int* posArr = (int*)take((size_t)ETOT * 4);
    int* clist = (int*)take((size_t)DTOT * 4);
    int* esrt = (int*)take((size_t)ES[0] * 4);
    short* Wtb = (short*)take((size_t)WT_TOT * 2);
    unsigned short* y = (unsigned short*)take((size_t)ES[0] * 32 * 2);  // 8.4 MB bf16
    size_t need = (size_t)(w - (char*)d_ws);
    bool fast = ws_size >= need;

    const int TB = 256;

    if (fast) {
        // ---------- pre-pass: 1 memset + 3 kernels -------------------------
        (void)hipMemsetAsync(zbase, 0, zbytes, stream);
        pre1<<<765 + NSLICE, 256, 0, stream>>>(
            pseudo[0], pseudo[1], pseudo[2], pseudo[3],
            dst[0], dst[1], dst[2], dst[3],
            cluster[0], cluster[1], cluster[2], cluster[3],
            Wp[1], Wp[2], Wp[3], Wp[4], Wp[5], Wp[6], Wp[7],
            hpart, degi, ccnt, clist, Wtb, posArr);
        pre2<<<8, 1024, 0, stream>>>(hpart, bbase, tileOf, pack, degi, csr);
        scatter_pos_all<<<680, 256, 0, stream>>>(pseudo[0], pseudo[1], pseudo[2], pseudo[3],
                                                 dst[0], dst[1], dst[2], dst[3],
                                                 bbase, csr, pack, posArr, esrt);

        // ---------------- Level 0: conv1 (1->32), conv12 (32->32) ----------
        {
            int n = NS[0];
            const int* off = csr + OFF2[0];
            const int* pos = posArr + EBASE[0];
            conv1_fin<<<cdiv(n, 8), TB, 0, stream>>>(x, src[0], pseudo[0], esrt, off,
                                                     Wp[0], Rp[0], Bp[0], bufA, n, ES[0]);
            mfma_conv<32, 32><<<MT[0], TB, 0, stream>>>(
                bufA, src[0], pseudo[0], pack, tileOf, pos, Wtb + WT_OFF[0], y, TB_[0], ES[0]);
            fin_pool_k<32, 32><<<NS[1] / 2, TB, 0, stream>>>(
                bufA, Rp[1], Bp[1], off, y, clist + NODE_OFF[0], bufB, NS[0]);
        }
        // ---------------- Level 1: conv2 (32->64), conv3 (64->64) ----------
        {
            int n = NS[1];
            const int* off = csr + OFF2[1];
            const int* pos = posArr + EBASE[1];
            mfma_conv<32, 64><<<MT[1], TB, 0, stream>>>(
                bufB, src[1], pseudo[1], pack, tileOf, pos, Wtb + WT_OFF[1], y, TB_[1], ES[1]);
            fin_gather_k<32, 64><<<cdiv(n, 4), TB, 0, stream>>>(bufB, Rp[2], Bp[2], off, y, bufA, n);
            mfma_conv<64, 64><<<MT[1], TB, 0, stream>>>(
                bufA, src[1], pseudo[1], pack, tileOf, pos, Wtb + WT_OFF[2], y, TB_[1], ES[1]);
            fin_pool_k<64, 64><<<NS[2], TB, 0, stream>>>(
                bufA, Rp[3], Bp[3], off, y, clist + NODE_OFF[1], bufB, NS[1]);
        }
        // ---------------- Level 2: conv4, conv5 (64->64) -------------------
        {
            int n = NS[2];
            const int* off = csr + OFF2[2];
            const int* pos = posArr + EBASE[2];
            mfma_conv<64, 64><<<MT[2], TB, 0, stream>>>(
                bufB, src[2], pseudo[2], pack, tileOf, pos, Wtb + WT_OFF[3], y, TB_[2], ES[2]);
            fin_gather_k<64, 64><<<cdiv(n, 4), TB, 0, stream>>>(bufB, Rp[4], Bp[4], off, y, bufA, n);
            mfma_conv<64, 64><<<MT[2], TB, 0, stream>>>(
                bufA, src[2], pseudo[2], pack, tileOf, pos, Wtb + WT_OFF[4], y, TB_[2], ES[2]);
            fin_pool_k<64, 64><<<NS[3], TB, 0, stream>>>(
                bufA, Rp[5], Bp[5], off, y, clist + NODE_OFF[2], bufB, NS[2]);
        }
        // ---------------- Level 3: conv6, conv7 (64->64) -------------------
        {
            int n = NS[3];
            const int* off = csr + OFF2[3];
            const int* pos = posArr + EBASE[3];
            mfma_conv<64, 64><<<MT[3], TB, 0, stream>>>(
                bufB, src[3], pseudo[3], pack, tileOf, pos, Wtb + WT_OFF[5], y, TB_[3], ES[3]);
            fin_gather_k<64, 64><<<cdiv(n, 4), TB, 0, stream>>>(bufB, Rp[6], Bp[6], off, y, bufA, n);
            mfma_conv<64, 64><<<MT[3], TB, 0, stream>>>(
                bufA, src[3], pseudo[3], pack, tileOf, pos, Wtb + WT_OFF[6], y, TB_[3], ES[3]);
            fin_pool_k<64, 64><<<NS[4], TB, 0, stream>>>(
                bufA, Rp[7], Bp[7], off, y, clist + NODE_OFF[3], bufB, NS[3]);
        }
        head_kernel<<<1, 64, 0, stream>>>(bufB, fc1w, fc1b, fc2w, fc2b, outp);
    } else if (ws_size >= fallbackNeed) {
        // ---------------- legacy edge-centric fallback ---------------------
        float* h0 = bufA;
        float* h1 = bufB;
        float* deg = (float*)degi;
        for (int l = 0; l < 4; ++l) {
            int E = ES[l], n = NS[l];
            (void)hipMemsetAsync(deg, 0, n * 4, stream);
            deg_kernel<<<cdiv(E, TB), TB, 0, stream>>>(dst[l], deg, E);
            for (int cc = 0; cc < 2; ++cc) {
                int li = (l == 0) ? cc : 2 * l + cc;
                if (l == 0 && cc == 0) {
                    (void)hipMemsetAsync(h0, 0, (size_t)n * 32 * 4, stream);
                    conv1_fused<<<cdiv(E, 8), TB, 0, stream>>>(x, src[0], dst[0], pseudo[0], Wp[0], h0, E);
                    finalize_k<1, 32><<<cdiv(n, 8), TB, 0, stream>>>(x, Rp[0], Bp[0], deg, h0, n);
                } else {
                    int ic = (l == 0) ? 32 : ((l == 1 && cc == 0) ? 32 : 64);
                    int oc = (l == 0) ? 32 : 64;
                    (void)hipMemsetAsync(h1, 0, (size_t)n * oc * 4, stream);
                    if (ic == 32 && oc == 32) {
                        conv_edges_inline<32, 32><<<cdiv(E, 8), TB, 0, stream>>>(h0, src[l], dst[l], pseudo[l], Wp[li], h1, E);
                        finalize_k<32, 32><<<cdiv(n, 8), TB, 0, stream>>>(h0, Rp[li], Bp[li], deg, h1, n);
                    } else if (ic == 32) {
                        conv_edges_inline<32, 64><<<cdiv(E, 4), TB, 0, stream>>>(h0, src[l], dst[l], pseudo[l], Wp[li], h1, E);
                        finalize_k<32, 64><<<cdiv(n, 4), TB, 0, stream>>>(h0, Rp[li], Bp[li], deg, h1, n);
                    } else {
                        conv_edges_inline<64, 64><<<cdiv(E, 4), TB, 0, stream>>>(h0, src[l], dst[l], pseudo[l], Wp[li], h1, E);
                        finalize_k<64, 64><<<cdiv(n, 4), TB, 0, stream>>>(h0, Rp[li], Bp[li], deg, h1, n);
                    }
                    float* tmp = h0; h0 = h1; h1 = tmp;
                }
            }
            int oc = (l == 0) ? 32 : 64;
            int logC = (l == 0) ? 5 : 6;
            (void)hipMemsetAsync(pool, 0, (size_t)NS[l + 1] * oc * 4, stream);
            pool_scatter<<<cdiv(n * oc, TB), TB, 0, stream>>>(h0, cluster[l], pool, n, logC);
            pool_decode<<<cdiv(NS[l + 1] * oc, TB), TB, 0, stream>>>(pool, h1, NS[l + 1] * oc);
            float* tmp = h0; h0 = h1; h1 = tmp;
        }
        head_kernel<<<1, 64, 0, stream>>>(h0, fc1w, fc1b, fc2w, fc2b, outp);
    }
}